// Round 7
// baseline (222.332 us; speedup 1.0000x reference)
//
#include <hip/hip_runtime.h>

#define NM 400000
#define NT 50000
#define NF 500000
#define NTOT (NM + NT + NF)
#define NBX 1024
#define NBY 1024
#define NBINS (NBX * NBY)
#define TDf 0.9f

// --- tiling: 64x64-bin tiles, 16x16 tile grid ---
#define TSHIFT 6
#define TBINS 64
#define TGRID 16
#define NTILE 256
#define HALO 4
#define TDIM (TBINS + HALO)      // 68
#define TSZ (TDIM * TDIM)        // 4624

#define GRID_NB 256              // blocks in fused kernel (== CUs; co-resident)
#define CBLK 256                 // chunks (== GRID_NB)
#define BTHR 1024                // threads per block
#define CHUNK 3712               // ceil(NTOT/CBLK) rounded up to 4
#define NPAY (CHUNK * CBLK)      // 950272

// --- ws layout (bytes) ---
// hist is stored TRANSPOSED: hist[t*CBLK + b]
#define WS_HIST 0                                    // 256KB
#define WS_TSUM (NTILE * CBLK * 4)
#define WS_TOFF (WS_TSUM + 4096)
#define WS_BAR  (WS_TOFF + 4096)                     // bar[0]=cnt, bar[1]=gen
#define WS_PRIV (WS_BAR + 4096)                      // 256*4624*4 = 4.73 MB
#define WS_SPAY4 (WS_PRIV + NTILE * TSZ * 4)         // 15.2 MB
#define WS_SPAYW (WS_SPAY4 + NPAY * 16)              // 3.8 MB
#define WS_NEED ((size_t)(WS_SPAYW + NPAY * 4))      // ~24 MB

// ---------------------------------------------------------------------------
struct NodeGeo { float lx, ly, sx, sy, w; };

__device__ __forceinline__ NodeGeo node_geo(
    int g, const float* __restrict__ pos, const float* __restrict__ nsx,
    const float* __restrict__ nsy, const float* __restrict__ csx,
    const float* __restrict__ csy, const float* __restrict__ offx,
    const float* __restrict__ offy, const float* __restrict__ ratio) {
  NodeGeo n;
  float x = pos[g], y = pos[NTOT + g];
  if (g >= NM && g < NM + NT) {
    float lox = fminf(fmaxf(x, 0.f), 1024.f);
    float hix = fminf(fmaxf(x + nsx[g], 0.f), 1024.f);
    float loy = fminf(fmaxf(y, 0.f), 1024.f);
    float hiy = fminf(fmaxf(y + nsy[g], 0.f), 1024.f);
    n.lx = lox; n.sx = hix - lox;
    n.ly = loy; n.sy = hiy - loy;
    n.w = TDf;
  } else {
    n.lx = x + offx[g]; n.ly = y + offy[g];
    n.sx = csx[g];      n.sy = csy[g];
    n.w = ratio[g];
  }
  return n;
}

__device__ __forceinline__ int tile_from_lo(float lx, float ly) {
  int bx = min(max((int)floorf(lx), 0), NBX - 1);
  int by = min(max((int)floorf(ly), 0), NBY - 1);
  return (bx >> TSHIFT) * TGRID + (by >> TSHIFT);
}

// ---------------------------------------------------------------------------
// device-scope grid barrier (generation-based). All GRID_NB blocks are
// guaranteed co-resident: 1024 thr (16 waves), 18.5 KB LDS, <=128 VGPR ->
// >=2 blocks/CU capacity, 256 blocks <= 256 CUs.
// ---------------------------------------------------------------------------
__device__ __forceinline__ void grid_bar(int* bar, int phase) {
  __syncthreads();
  if (threadIdx.x == 0) {
    __threadfence();  // publish this block's prior global writes
    int prev = __hip_atomic_fetch_add(&bar[0], 1, __ATOMIC_ACQ_REL,
                                      __HIP_MEMORY_SCOPE_AGENT);
    if (prev == GRID_NB - 1) {
      __hip_atomic_store(&bar[0], 0, __ATOMIC_RELAXED,
                         __HIP_MEMORY_SCOPE_AGENT);
      __hip_atomic_store(&bar[1], phase, __ATOMIC_RELEASE,
                         __HIP_MEMORY_SCOPE_AGENT);
    } else {
      while (__hip_atomic_load(&bar[1], __ATOMIC_ACQUIRE,
                               __HIP_MEMORY_SCOPE_AGENT) < phase) {
        __builtin_amdgcn_s_sleep(1);
      }
    }
    __threadfence();
  }
  __syncthreads();
}

// ---------------------------------------------------------------------------
__global__ void k_init(int* __restrict__ bar, float* __restrict__ out) {
  bar[0] = 0;
  bar[1] = 0;
  out[0] = 0.f;
  out[1] = 0.f;
}

// ---------------------------------------------------------------------------
// fused: count -> scan1 -> (scan2 + fill) -> accum -> final
// ---------------------------------------------------------------------------
__global__ __launch_bounds__(BTHR) void k_fused(
    const float* __restrict__ pos, const float* __restrict__ nsx,
    const float* __restrict__ nsy, const float* __restrict__ csx,
    const float* __restrict__ csy, const float* __restrict__ offx,
    const float* __restrict__ offy, const float* __restrict__ ratio,
    int* __restrict__ hist, int* __restrict__ tilesum, int* __restrict__ toff,
    int* __restrict__ bar, float4* __restrict__ spay4,
    float* __restrict__ spayw, float* __restrict__ priv,
    float* __restrict__ out) {
  __shared__ union {
    int h[NTILE];
    struct { int s[CBLK]; } s1;
    struct { int sc[NTILE]; int cur[NTILE]; } f;
    float tile[TSZ];
    struct { float ss[16]; float sm[16]; } r;
  } sh;

  const int b = blockIdx.x;

  // node registers carried across phases 1 -> 3 (no input re-read)
  float lxs[4], lys[4], sxs[4], sys[4], wsv[4];
  int tids[4];
  bool have = false;

  // ---------------- phase 1: count ----------------
  if (threadIdx.x < NTILE) sh.h[threadIdx.x] = 0;
  __syncthreads();
  {
    int lo = b * CHUNK, hi = min(lo + CHUNK, NTOT);
    int i0 = lo + threadIdx.x * 4;
    if (i0 < hi) {  // groups of 4 are aligned; i0<hi implies i0+3<hi
      have = true;
      float xs[4], ys[4];
      *(float4*)xs = *(const float4*)(pos + i0);
      *(float4*)ys = *(const float4*)(pos + NTOT + i0);
      bool isTerm = (i0 >= NM && i0 < NM + NT);
      if (isTerm) {
        float nx[4], ny[4];
        *(float4*)nx = *(const float4*)(nsx + i0);
        *(float4*)ny = *(const float4*)(nsy + i0);
#pragma unroll
        for (int j = 0; j < 4; ++j) {
          float lox = fminf(fmaxf(xs[j], 0.f), 1024.f);
          float hix = fminf(fmaxf(xs[j] + nx[j], 0.f), 1024.f);
          float loy = fminf(fmaxf(ys[j], 0.f), 1024.f);
          float hiy = fminf(fmaxf(ys[j] + ny[j], 0.f), 1024.f);
          lxs[j] = lox; sxs[j] = hix - lox;
          lys[j] = loy; sys[j] = hiy - loy;
          wsv[j] = TDf;
        }
      } else {
        float oxs[4], oys[4], cx[4], cy[4], rr[4];
        *(float4*)oxs = *(const float4*)(offx + i0);
        *(float4*)oys = *(const float4*)(offy + i0);
        *(float4*)cx = *(const float4*)(csx + i0);
        *(float4*)cy = *(const float4*)(csy + i0);
        *(float4*)rr = *(const float4*)(ratio + i0);
#pragma unroll
        for (int j = 0; j < 4; ++j) {
          lxs[j] = xs[j] + oxs[j];
          lys[j] = ys[j] + oys[j];
          sxs[j] = cx[j]; sys[j] = cy[j];
          wsv[j] = rr[j];
        }
      }
#pragma unroll
      for (int j = 0; j < 4; ++j) {
        tids[j] = tile_from_lo(lxs[j], lys[j]);
        atomicAdd(&sh.h[tids[j]], 1);
      }
    }
  }
  __syncthreads();
  if (threadIdx.x < NTILE) hist[threadIdx.x * CBLK + b] = sh.h[threadIdx.x];

  grid_bar(bar, 1);

  // ---------------- phase 2: per-tile scan across blocks (tile = b) -------
  {
    int vmine = 0;
    if (threadIdx.x < CBLK) {
      vmine = hist[b * CBLK + threadIdx.x];
      sh.s1.s[threadIdx.x] = vmine;
    }
    __syncthreads();
    for (int d = 1; d < CBLK; d <<= 1) {
      int u = 0;
      if (threadIdx.x < CBLK && threadIdx.x >= d) u = sh.s1.s[threadIdx.x - d];
      __syncthreads();
      if (threadIdx.x < CBLK) sh.s1.s[threadIdx.x] += u;
      __syncthreads();
    }
    if (threadIdx.x < CBLK) {
      int incl = sh.s1.s[threadIdx.x];
      hist[b * CBLK + threadIdx.x] = incl - vmine;  // exclusive within tile
      if (threadIdx.x == CBLK - 1) tilesum[b] = incl;
    }
  }

  grid_bar(bar, 2);

  // ---------------- phase 3: local scan of tilesum + scatter payload ------
  {
    int v2 = 0;
    if (threadIdx.x < NTILE) {
      v2 = tilesum[threadIdx.x];
      sh.f.sc[threadIdx.x] = v2;
    }
    __syncthreads();
    for (int d = 1; d < NTILE; d <<= 1) {
      int u = 0;
      if (threadIdx.x < NTILE && threadIdx.x >= d) u = sh.f.sc[threadIdx.x - d];
      __syncthreads();
      if (threadIdx.x < NTILE) sh.f.sc[threadIdx.x] += u;
      __syncthreads();
    }
    if (threadIdx.x < NTILE) {
      int tf = sh.f.sc[threadIdx.x] - v2;  // exclusive tile offset
      sh.f.cur[threadIdx.x] = tf + hist[threadIdx.x * CBLK + b];
      if (b == 0) {
        toff[threadIdx.x] = tf;
        if (threadIdx.x == NTILE - 1) toff[NTILE] = sh.f.sc[threadIdx.x];
      }
    }
    __syncthreads();
    if (have) {
#pragma unroll
      for (int j = 0; j < 4; ++j) {
        int slot = atomicAdd(&sh.f.cur[tids[j]], 1);
        spay4[slot] = make_float4(lxs[j], lys[j], sxs[j], sys[j]);
        spayw[slot] = wsv[j];
      }
    }
  }

  grid_bar(bar, 3);

  // ---------------- phase 4: per-tile accumulate (tile = b) ---------------
  {
    for (int j = threadIdx.x; j < TSZ; j += BTHR) sh.tile[j] = 0.f;
    __syncthreads();
    int bx0 = (b >> 4) << TSHIFT;
    int by0 = (b & (TGRID - 1)) << TSHIFT;
    int lo = toff[b], hi = toff[b + 1];
    for (int s = lo + threadIdx.x; s < hi; s += BTHR) {
      float4 p = spay4[s];
      float w = spayw[s];
      float lx = p.x, ly = p.y;
      float hx = lx + p.z, hy = ly + p.w;
      int b0x = (int)floorf(lx);
      int b0y = (int)floorf(ly);
      float pxv[6], pyv[6];
#pragma unroll
      for (int k = 0; k < 6; ++k) {
        int kx = b0x + k;
        float px = fminf(hx, (float)kx + 1.0f) - fmaxf(lx, (float)kx);
        pxv[k] = (kx >= 0 && kx < NBX) ? fmaxf(px, 0.f) : 0.f;
        int ky = b0y + k;
        float py = fminf(hy, (float)ky + 1.0f) - fmaxf(ly, (float)ky);
        pyv[k] = (ky >= 0 && ky < NBY) ? fmaxf(py, 0.f) : 0.f;
      }
#pragma unroll
      for (int a = 0; a < 6; ++a) {
        if (pxv[a] == 0.f) continue;
        float wx = w * pxv[a];
        int lxi = b0x + a - bx0;
#pragma unroll
        for (int c = 0; c < 6; ++c) {
          float v = wx * pyv[c];
          if (v != 0.f) atomicAdd(&sh.tile[lxi * TDIM + (b0y + c - by0)], v);
        }
      }
    }
    __syncthreads();
    float* pdst = priv + b * TSZ;
    for (int j = threadIdx.x; j < TSZ; j += BTHR) pdst[j] = sh.tile[j];
  }

  grid_bar(bar, 4);

  // ---------------- phase 5: halo combine + overflow sum / max ------------
  {
    float ssum = 0.f, smax = 0.f;
    for (int idx = b * BTHR + threadIdx.x; idx < NBINS;
         idx += GRID_NB * BTHR) {
      int X = idx >> 10, Y = idx & 1023;
      int tx = X >> TSHIFT, ty = Y >> TSHIFT;
      int lx = X & (TBINS - 1), ly = Y & (TBINS - 1);
      int t = tx * TGRID + ty;
      float d = priv[t * TSZ + lx * TDIM + ly];
      if (lx < HALO && tx > 0)
        d += priv[(t - TGRID) * TSZ + (lx + TBINS) * TDIM + ly];
      if (ly < HALO && ty > 0)
        d += priv[(t - 1) * TSZ + lx * TDIM + (ly + TBINS)];
      if (lx < HALO && ly < HALO && tx > 0 && ty > 0)
        d += priv[(t - TGRID - 1) * TSZ + (lx + TBINS) * TDIM + (ly + TBINS)];
      ssum += fmaxf(d - TDf, 0.f);
      smax = fmaxf(smax, d);
    }
#pragma unroll
    for (int off = 32; off > 0; off >>= 1) {
      ssum += __shfl_down(ssum, off, 64);
      smax = fmaxf(smax, __shfl_down(smax, off, 64));
    }
    __syncthreads();  // retire phase-4 union use before reusing as sh.r
    int wid = threadIdx.x >> 6;
    if ((threadIdx.x & 63) == 0) { sh.r.ss[wid] = ssum; sh.r.sm[wid] = smax; }
    __syncthreads();
    if (threadIdx.x == 0) {
      float S = 0.f, M = 0.f;
#pragma unroll
      for (int k = 0; k < 16; ++k) {
        S += sh.r.ss[k];
        M = fmaxf(M, sh.r.sm[k]);
      }
      atomicAdd(&out[0], S);
      atomicMax((int*)&out[1], __float_as_int(M));
    }
  }
}

// ---------------------------------------------------------------------------
// Legacy fallback (global-atomic path) if ws too small
// ---------------------------------------------------------------------------
__global__ __launch_bounds__(256) void scatter_all(
    const float* __restrict__ pos, const float* __restrict__ nsx,
    const float* __restrict__ nsy, const float* __restrict__ csx,
    const float* __restrict__ csy, const float* __restrict__ offx,
    const float* __restrict__ offy, const float* __restrict__ ratio,
    float* __restrict__ map, float* __restrict__ out) {
  int i = blockIdx.x * blockDim.x + threadIdx.x;
  if (i == 0) { out[0] = 0.f; out[1] = 0.f; }
  if (i >= NTOT) return;
  NodeGeo n = node_geo(i, pos, nsx, nsy, csx, csy, offx, offy, ratio);
  int b0x = (int)floorf(n.lx), b0y = (int)floorf(n.ly);
  float hx = n.lx + n.sx, hy = n.ly + n.sy;
  float pxv[6], pyv[6];
  int kxv[6], kyv[6];
#pragma unroll
  for (int k = 0; k < 6; ++k) {
    int kx = b0x + k;
    float px = fminf(hx, (float)kx + 1.f) - fmaxf(n.lx, (float)kx);
    pxv[k] = (kx >= 0 && kx < NBX) ? fmaxf(px, 0.f) : 0.f;
    kxv[k] = min(max(kx, 0), NBX - 1);
    int ky = b0y + k;
    float py = fminf(hy, (float)ky + 1.f) - fmaxf(n.ly, (float)ky);
    pyv[k] = (ky >= 0 && ky < NBY) ? fmaxf(py, 0.f) : 0.f;
    kyv[k] = min(max(ky, 0), NBY - 1);
  }
#pragma unroll
  for (int a = 0; a < 6; ++a) {
    if (pxv[a] == 0.f) continue;
    float wx = n.w * pxv[a];
#pragma unroll
    for (int c = 0; c < 6; ++c) {
      float v = wx * pyv[c];
      if (v != 0.f) atomicAdd(&map[kxv[a] * NBY + kyv[c]], v);
    }
  }
}

__global__ __launch_bounds__(256) void reduce_map(const float* __restrict__ map,
                                                  float* __restrict__ out) {
  const float4* m4 = (const float4*)map;
  const int n4 = NBINS / 4;
  float s = 0.f, mx = 0.f;
  for (int i = blockIdx.x * blockDim.x + threadIdx.x; i < n4;
       i += gridDim.x * blockDim.x) {
    float4 v = m4[i];
    s += fmaxf(v.x - TDf, 0.f) + fmaxf(v.y - TDf, 0.f) +
         fmaxf(v.z - TDf, 0.f) + fmaxf(v.w - TDf, 0.f);
    mx = fmaxf(mx, fmaxf(fmaxf(v.x, v.y), fmaxf(v.z, v.w)));
  }
#pragma unroll
  for (int off = 32; off > 0; off >>= 1) {
    s += __shfl_down(s, off, 64);
    mx = fmaxf(mx, __shfl_down(mx, off, 64));
  }
  __shared__ float ss[4], sm[4];
  int wid = threadIdx.x >> 6;
  if ((threadIdx.x & 63) == 0) { ss[wid] = s; sm[wid] = mx; }
  __syncthreads();
  if (threadIdx.x == 0) {
    atomicAdd(&out[0], ss[0] + ss[1] + ss[2] + ss[3]);
    atomicMax((int*)&out[1],
              __float_as_int(fmaxf(fmaxf(sm[0], sm[1]), fmaxf(sm[2], sm[3]))));
  }
}

// ---------------------------------------------------------------------------
extern "C" void kernel_launch(void* const* d_in, const int* in_sizes, int n_in,
                              void* d_out, int out_size, void* d_ws,
                              size_t ws_size, hipStream_t stream) {
  (void)in_sizes; (void)n_in; (void)out_size;
  const float* pos   = (const float*)d_in[0];
  const float* nsx   = (const float*)d_in[1];
  const float* nsy   = (const float*)d_in[2];
  const float* csx   = (const float*)d_in[3];
  const float* csy   = (const float*)d_in[4];
  const float* offx  = (const float*)d_in[5];
  const float* offy  = (const float*)d_in[6];
  const float* ratio = (const float*)d_in[7];
  float* out = (float*)d_out;
  char* ws = (char*)d_ws;

  if (ws_size >= WS_NEED) {
    int*    hist    = (int*)(ws + WS_HIST);
    int*    tilesum = (int*)(ws + WS_TSUM);
    int*    toff    = (int*)(ws + WS_TOFF);
    int*    bar     = (int*)(ws + WS_BAR);
    float*  priv    = (float*)(ws + WS_PRIV);
    float4* spay4   = (float4*)(ws + WS_SPAY4);
    float*  spayw   = (float*)(ws + WS_SPAYW);

    k_init<<<1, 1, 0, stream>>>(bar, out);
    k_fused<<<GRID_NB, BTHR, 0, stream>>>(pos, nsx, nsy, csx, csy, offx, offy,
                                          ratio, hist, tilesum, toff, bar,
                                          spay4, spayw, priv, out);
  } else {
    float* map = (float*)ws;
    hipMemsetAsync(map, 0, NBINS * sizeof(float), stream);
    scatter_all<<<(NTOT + 255) / 256, 256, 0, stream>>>(
        pos, nsx, nsy, csx, csy, offx, offy, ratio, map, out);
    reduce_map<<<1024, 256, 0, stream>>>(map, out);
  }
}

// Round 8
// 72.715 us; speedup vs baseline: 3.0576x; 3.0576x over previous
//
#include <hip/hip_runtime.h>

#define NM 400000
#define NT 50000
#define NF 500000
#define NTOT (NM + NT + NF)
#define NBX 1024
#define NBY 1024
#define NBINS (NBX * NBY)
#define TDf 0.9f

// --- tiling: 64x64-bin tiles, 16x16 tile grid ---
#define TSHIFT 6
#define TBINS 64
#define TGRID 16
#define NTILE 256
#define HALO 4
#define TDIM (TBINS + HALO)      // 68
#define TSZ (TDIM * TDIM)        // 4624

#define CBLK 256                 // blocks for fill (chunks)
#define BTHR 1024                // threads per block
#define CHUNK 3712               // ceil(NTOT/CBLK) rounded to multiple of 4
#define CAPB 64                  // slots per (tile,block) sub-bucket
// mean fill = 3712/256 = 14.5 (Poisson) -> P(count > 64) ~ 1e-20: safe.

// --- ws layout (bytes) ---
#define WS_HCNT 0                                     // 256x256 ints = 256 KB
#define WS_PRIV (NTILE * CBLK * 4 + 4096)             // 256*4624*4 = 4.73 MB
#define WS_SPAY4 (WS_PRIV + NTILE * TSZ * 4)          // 65536*64*16 = 64 MB
#define WS_SPAYW (WS_SPAY4 + NTILE * CBLK * CAPB * 16)  // 16 MB
#define WS_NEED ((size_t)(WS_SPAYW + NTILE * CBLK * CAPB * 4))  // ~85 MB

// ---------------------------------------------------------------------------
struct NodeGeo { float lx, ly, sx, sy, w; };

__device__ __forceinline__ NodeGeo node_geo(
    int g, const float* __restrict__ pos, const float* __restrict__ nsx,
    const float* __restrict__ nsy, const float* __restrict__ csx,
    const float* __restrict__ csy, const float* __restrict__ offx,
    const float* __restrict__ offy, const float* __restrict__ ratio) {
  NodeGeo n;
  float x = pos[g], y = pos[NTOT + g];
  if (g >= NM && g < NM + NT) {
    float lox = fminf(fmaxf(x, 0.f), 1024.f);
    float hix = fminf(fmaxf(x + nsx[g], 0.f), 1024.f);
    float loy = fminf(fmaxf(y, 0.f), 1024.f);
    float hiy = fminf(fmaxf(y + nsy[g], 0.f), 1024.f);
    n.lx = lox; n.sx = hix - lox;
    n.ly = loy; n.sy = hiy - loy;
    n.w = TDf;
  } else {
    n.lx = x + offx[g]; n.ly = y + offy[g];
    n.sx = csx[g];      n.sy = csy[g];
    n.w = ratio[g];
  }
  return n;
}

__device__ __forceinline__ int tile_from_lo(float lx, float ly) {
  int bx = min(max((int)floorf(lx), 0), NBX - 1);
  int by = min(max((int)floorf(ly), 0), NBY - 1);
  return (bx >> TSHIFT) * TGRID + (by >> TSHIFT);
}

// ---------------------------------------------------------------------------
// 1) single-pass bucket scatter: coalesced input read, LDS cursors,
//    per-(tile,block) fixed-capacity sub-buckets -> NO global atomics,
//    NO count pass, NO scans. Also zeroes out[0..1].
// ---------------------------------------------------------------------------
__global__ __launch_bounds__(BTHR) void k_fill(
    const float* __restrict__ pos, const float* __restrict__ nsx,
    const float* __restrict__ nsy, const float* __restrict__ csx,
    const float* __restrict__ csy, const float* __restrict__ offx,
    const float* __restrict__ offy, const float* __restrict__ ratio,
    int* __restrict__ hcnt, float4* __restrict__ spay4,
    float* __restrict__ spayw, float* __restrict__ out) {
  const int b = blockIdx.x;
  if (b == 0 && threadIdx.x == 0) { out[0] = 0.f; out[1] = 0.f; }
  __shared__ int cur[NTILE];
  if (threadIdx.x < NTILE) cur[threadIdx.x] = 0;
  __syncthreads();

  int lo = b * CHUNK, hi = min(lo + CHUNK, NTOT);
  int i0 = lo + threadIdx.x * 4;
  if (i0 < hi) {  // 4-groups never straddle hi (CHUNK, NM, NT all %4==0)
    float xs[4], ys[4], lxs[4], lys[4], sxs[4], sys[4], wsv[4];
    *(float4*)xs = *(const float4*)(pos + i0);
    *(float4*)ys = *(const float4*)(pos + NTOT + i0);
    bool isTerm = (i0 >= NM && i0 < NM + NT);
    if (isTerm) {
      float nx[4], ny[4];
      *(float4*)nx = *(const float4*)(nsx + i0);
      *(float4*)ny = *(const float4*)(nsy + i0);
#pragma unroll
      for (int j = 0; j < 4; ++j) {
        float lox = fminf(fmaxf(xs[j], 0.f), 1024.f);
        float hix = fminf(fmaxf(xs[j] + nx[j], 0.f), 1024.f);
        float loy = fminf(fmaxf(ys[j], 0.f), 1024.f);
        float hiy = fminf(fmaxf(ys[j] + ny[j], 0.f), 1024.f);
        lxs[j] = lox; sxs[j] = hix - lox;
        lys[j] = loy; sys[j] = hiy - loy;
        wsv[j] = TDf;
      }
    } else {
      float oxs[4], oys[4], cx[4], cy[4], rr[4];
      *(float4*)oxs = *(const float4*)(offx + i0);
      *(float4*)oys = *(const float4*)(offy + i0);
      *(float4*)cx = *(const float4*)(csx + i0);
      *(float4*)cy = *(const float4*)(csy + i0);
      *(float4*)rr = *(const float4*)(ratio + i0);
#pragma unroll
      for (int j = 0; j < 4; ++j) {
        lxs[j] = xs[j] + oxs[j];
        lys[j] = ys[j] + oys[j];
        sxs[j] = cx[j]; sys[j] = cy[j];
        wsv[j] = rr[j];
      }
    }
#pragma unroll
    for (int j = 0; j < 4; ++j) {
      int t = tile_from_lo(lxs[j], lys[j]);
      int slot = atomicAdd(&cur[t], 1);
      int idx = (t * CBLK + b) * CAPB + min(slot, CAPB - 1);  // clamp (never hit)
      spay4[idx] = make_float4(lxs[j], lys[j], sxs[j], sys[j]);
      spayw[idx] = wsv[j];
    }
  }
  __syncthreads();
  if (threadIdx.x < NTILE)
    hcnt[threadIdx.x * CBLK + b] = min(cur[threadIdx.x], CAPB);
}

// ---------------------------------------------------------------------------
// 2) per-tile accumulation: iterate the tile's 256 sub-buckets (ragged),
//    6x6 stencil into 68x68 LDS tile, plain store to priv.
// ---------------------------------------------------------------------------
__global__ __launch_bounds__(BTHR) void k_accum(
    const int* __restrict__ hcnt, const float4* __restrict__ spay4,
    const float* __restrict__ spayw, float* __restrict__ priv) {
  __shared__ float tile[TSZ];
  __shared__ int cnts[CBLK];
  const int t = blockIdx.x;
  for (int j = threadIdx.x; j < TSZ; j += BTHR) tile[j] = 0.f;
  if (threadIdx.x < CBLK) cnts[threadIdx.x] = hcnt[t * CBLK + threadIdx.x];
  __syncthreads();

  const int bx0 = (t >> 4) << TSHIFT;
  const int by0 = (t & (TGRID - 1)) << TSHIFT;
  const int base = t * CBLK * CAPB;
  for (int s = threadIdx.x; s < CBLK * CAPB; s += BTHR) {
    int b2 = s >> 6;          // sub-bucket (source block)
    int idx = s & (CAPB - 1); // slot
    if (idx >= cnts[b2]) continue;
    float4 p = spay4[base + s];
    float w = spayw[base + s];
    float lx = p.x, ly = p.y;
    float hx = lx + p.z, hy = ly + p.w;
    int b0x = (int)floorf(lx);
    int b0y = (int)floorf(ly);
    float pxv[6], pyv[6];
#pragma unroll
    for (int k = 0; k < 6; ++k) {
      int kx = b0x + k;
      float px = fminf(hx, (float)kx + 1.0f) - fmaxf(lx, (float)kx);
      pxv[k] = (kx >= 0 && kx < NBX) ? fmaxf(px, 0.f) : 0.f;
      int ky = b0y + k;
      float py = fminf(hy, (float)ky + 1.0f) - fmaxf(ly, (float)ky);
      pyv[k] = (ky >= 0 && ky < NBY) ? fmaxf(py, 0.f) : 0.f;
    }
#pragma unroll
    for (int a = 0; a < 6; ++a) {
      if (pxv[a] == 0.f) continue;
      float wx = w * pxv[a];
      int lxi = b0x + a - bx0;
#pragma unroll
      for (int c = 0; c < 6; ++c) {
        float v = wx * pyv[c];
        if (v != 0.f) atomicAdd(&tile[lxi * TDIM + (b0y + c - by0)], v);
      }
    }
  }
  __syncthreads();
  float* pdst = priv + t * TSZ;
  for (int j = threadIdx.x; j < TSZ; j += BTHR) pdst[j] = tile[j];
}

// ---------------------------------------------------------------------------
// 3) combine halos + fused overflow-sum / max reduction
// ---------------------------------------------------------------------------
__global__ __launch_bounds__(BTHR) void k_final(const float* __restrict__ priv,
                                                float* __restrict__ out) {
  float ssum = 0.f, smax = 0.f;
  for (int idx = blockIdx.x * BTHR + threadIdx.x; idx < NBINS;
       idx += gridDim.x * BTHR) {
    int X = idx >> 10, Y = idx & 1023;
    int tx = X >> TSHIFT, ty = Y >> TSHIFT;
    int lx = X & (TBINS - 1), ly = Y & (TBINS - 1);
    int t = tx * TGRID + ty;
    float d = priv[t * TSZ + lx * TDIM + ly];
    if (lx < HALO && tx > 0)
      d += priv[(t - TGRID) * TSZ + (lx + TBINS) * TDIM + ly];
    if (ly < HALO && ty > 0)
      d += priv[(t - 1) * TSZ + lx * TDIM + (ly + TBINS)];
    if (lx < HALO && ly < HALO && tx > 0 && ty > 0)
      d += priv[(t - TGRID - 1) * TSZ + (lx + TBINS) * TDIM + (ly + TBINS)];
    ssum += fmaxf(d - TDf, 0.f);
    smax = fmaxf(smax, d);
  }
#pragma unroll
  for (int off = 32; off > 0; off >>= 1) {
    ssum += __shfl_down(ssum, off, 64);
    smax = fmaxf(smax, __shfl_down(smax, off, 64));
  }
  __shared__ float ss[16], sm[16];
  int wid = threadIdx.x >> 6;
  if ((threadIdx.x & 63) == 0) { ss[wid] = ssum; sm[wid] = smax; }
  __syncthreads();
  if (threadIdx.x == 0) {
    float S = 0.f, M = 0.f;
#pragma unroll
    for (int k = 0; k < 16; ++k) { S += ss[k]; M = fmaxf(M, sm[k]); }
    atomicAdd(&out[0], S);
    atomicMax((int*)&out[1], __float_as_int(M));
  }
}

// ---------------------------------------------------------------------------
// Legacy fallback (global-atomic path) if ws too small
// ---------------------------------------------------------------------------
__global__ __launch_bounds__(256) void scatter_all(
    const float* __restrict__ pos, const float* __restrict__ nsx,
    const float* __restrict__ nsy, const float* __restrict__ csx,
    const float* __restrict__ csy, const float* __restrict__ offx,
    const float* __restrict__ offy, const float* __restrict__ ratio,
    float* __restrict__ map, float* __restrict__ out) {
  int i = blockIdx.x * blockDim.x + threadIdx.x;
  if (i == 0) { out[0] = 0.f; out[1] = 0.f; }
  if (i >= NTOT) return;
  NodeGeo n = node_geo(i, pos, nsx, nsy, csx, csy, offx, offy, ratio);
  int b0x = (int)floorf(n.lx), b0y = (int)floorf(n.ly);
  float hx = n.lx + n.sx, hy = n.ly + n.sy;
  float pxv[6], pyv[6];
  int kxv[6], kyv[6];
#pragma unroll
  for (int k = 0; k < 6; ++k) {
    int kx = b0x + k;
    float px = fminf(hx, (float)kx + 1.f) - fmaxf(n.lx, (float)kx);
    pxv[k] = (kx >= 0 && kx < NBX) ? fmaxf(px, 0.f) : 0.f;
    kxv[k] = min(max(kx, 0), NBX - 1);
    int ky = b0y + k;
    float py = fminf(hy, (float)ky + 1.f) - fmaxf(n.ly, (float)ky);
    pyv[k] = (ky >= 0 && ky < NBY) ? fmaxf(py, 0.f) : 0.f;
    kyv[k] = min(max(ky, 0), NBY - 1);
  }
#pragma unroll
  for (int a = 0; a < 6; ++a) {
    if (pxv[a] == 0.f) continue;
    float wx = n.w * pxv[a];
#pragma unroll
    for (int c = 0; c < 6; ++c) {
      float v = wx * pyv[c];
      if (v != 0.f) atomicAdd(&map[kxv[a] * NBY + kyv[c]], v);
    }
  }
}

__global__ __launch_bounds__(256) void reduce_map(const float* __restrict__ map,
                                                  float* __restrict__ out) {
  const float4* m4 = (const float4*)map;
  const int n4 = NBINS / 4;
  float s = 0.f, mx = 0.f;
  for (int i = blockIdx.x * blockDim.x + threadIdx.x; i < n4;
       i += gridDim.x * blockDim.x) {
    float4 v = m4[i];
    s += fmaxf(v.x - TDf, 0.f) + fmaxf(v.y - TDf, 0.f) +
         fmaxf(v.z - TDf, 0.f) + fmaxf(v.w - TDf, 0.f);
    mx = fmaxf(mx, fmaxf(fmaxf(v.x, v.y), fmaxf(v.z, v.w)));
  }
#pragma unroll
  for (int off = 32; off > 0; off >>= 1) {
    s += __shfl_down(s, off, 64);
    mx = fmaxf(mx, __shfl_down(mx, off, 64));
  }
  __shared__ float ss[4], sm[4];
  int wid = threadIdx.x >> 6;
  if ((threadIdx.x & 63) == 0) { ss[wid] = s; sm[wid] = mx; }
  __syncthreads();
  if (threadIdx.x == 0) {
    atomicAdd(&out[0], ss[0] + ss[1] + ss[2] + ss[3]);
    atomicMax((int*)&out[1],
              __float_as_int(fmaxf(fmaxf(sm[0], sm[1]), fmaxf(sm[2], sm[3]))));
  }
}

// ---------------------------------------------------------------------------
extern "C" void kernel_launch(void* const* d_in, const int* in_sizes, int n_in,
                              void* d_out, int out_size, void* d_ws,
                              size_t ws_size, hipStream_t stream) {
  (void)in_sizes; (void)n_in; (void)out_size;
  const float* pos   = (const float*)d_in[0];
  const float* nsx   = (const float*)d_in[1];
  const float* nsy   = (const float*)d_in[2];
  const float* csx   = (const float*)d_in[3];
  const float* csy   = (const float*)d_in[4];
  const float* offx  = (const float*)d_in[5];
  const float* offy  = (const float*)d_in[6];
  const float* ratio = (const float*)d_in[7];
  float* out = (float*)d_out;
  char* ws = (char*)d_ws;

  if (ws_size >= WS_NEED) {
    int*    hcnt  = (int*)(ws + WS_HCNT);
    float*  priv  = (float*)(ws + WS_PRIV);
    float4* spay4 = (float4*)(ws + WS_SPAY4);
    float*  spayw = (float*)(ws + WS_SPAYW);

    k_fill<<<CBLK, BTHR, 0, stream>>>(pos, nsx, nsy, csx, csy, offx, offy,
                                      ratio, hcnt, spay4, spayw, out);
    k_accum<<<NTILE, BTHR, 0, stream>>>(hcnt, spay4, spayw, priv);
    k_final<<<256, BTHR, 0, stream>>>(priv, out);
  } else {
    float* map = (float*)ws;
    hipMemsetAsync(map, 0, NBINS * sizeof(float), stream);
    scatter_all<<<(NTOT + 255) / 256, 256, 0, stream>>>(
        pos, nsx, nsy, csx, csy, offx, offy, ratio, map, out);
    reduce_map<<<1024, 256, 0, stream>>>(map, out);
  }
}

// Round 9
// 68.555 us; speedup vs baseline: 3.2431x; 1.0607x over previous
//
#include <hip/hip_runtime.h>

#define NM 400000
#define NT 50000
#define NF 500000
#define NTOT (NM + NT + NF)
#define NBX 1024
#define NBY 1024
#define NBINS (NBX * NBY)
#define TDf 0.9f

// --- tiling: 64x64-bin tiles, 16x16 tile grid ---
#define TSHIFT 6
#define TBINS 64
#define TGRID 16
#define NTILE 256
#define HALO 4
#define TDIM (TBINS + HALO)      // 68
#define TSZ (TDIM * TDIM)        // 4624

#define CBLK 256                 // blocks for fill (chunks)
#define BTHR 1024                // threads per block
#define CHUNK 3712               // ceil(NTOT/CBLK) rounded to multiple of 4
#define CAPB 64                  // slots per (tile,block) sub-bucket
#define MAXN 8192                // max nodes per tile (mean 3712, 73 sigma)

// --- ws layout (bytes) ---
#define WS_HCNT 0                                     // 256x256 ints = 256 KB
#define WS_PRIV (NTILE * CBLK * 4 + 4096)             // 256*4624*4 = 4.73 MB
#define WS_SPAY4 (WS_PRIV + NTILE * TSZ * 4)          // 65536*64*16 = 64 MB
#define WS_SPAYW (WS_SPAY4 + NTILE * CBLK * CAPB * 16)  // 16 MB
#define WS_NEED ((size_t)(WS_SPAYW + NTILE * CBLK * CAPB * 4))  // ~85 MB

// ---------------------------------------------------------------------------
struct NodeGeo { float lx, ly, sx, sy, w; };

__device__ __forceinline__ NodeGeo node_geo(
    int g, const float* __restrict__ pos, const float* __restrict__ nsx,
    const float* __restrict__ nsy, const float* __restrict__ csx,
    const float* __restrict__ csy, const float* __restrict__ offx,
    const float* __restrict__ offy, const float* __restrict__ ratio) {
  NodeGeo n;
  float x = pos[g], y = pos[NTOT + g];
  if (g >= NM && g < NM + NT) {
    float lox = fminf(fmaxf(x, 0.f), 1024.f);
    float hix = fminf(fmaxf(x + nsx[g], 0.f), 1024.f);
    float loy = fminf(fmaxf(y, 0.f), 1024.f);
    float hiy = fminf(fmaxf(y + nsy[g], 0.f), 1024.f);
    n.lx = lox; n.sx = hix - lox;
    n.ly = loy; n.sy = hiy - loy;
    n.w = TDf;
  } else {
    n.lx = x + offx[g]; n.ly = y + offy[g];
    n.sx = csx[g];      n.sy = csy[g];
    n.w = ratio[g];
  }
  return n;
}

__device__ __forceinline__ int tile_from_lo(float lx, float ly) {
  int bx = min(max((int)floorf(lx), 0), NBX - 1);
  int by = min(max((int)floorf(ly), 0), NBY - 1);
  return (bx >> TSHIFT) * TGRID + (by >> TSHIFT);
}

// ---------------------------------------------------------------------------
// 1) single-pass bucket scatter: coalesced input read, LDS cursors,
//    per-(tile,block) fixed-capacity sub-buckets. Also zeroes out[0..1].
// ---------------------------------------------------------------------------
__global__ __launch_bounds__(BTHR) void k_fill(
    const float* __restrict__ pos, const float* __restrict__ nsx,
    const float* __restrict__ nsy, const float* __restrict__ csx,
    const float* __restrict__ csy, const float* __restrict__ offx,
    const float* __restrict__ offy, const float* __restrict__ ratio,
    int* __restrict__ hcnt, float4* __restrict__ spay4,
    float* __restrict__ spayw, float* __restrict__ out) {
  const int b = blockIdx.x;
  if (b == 0 && threadIdx.x == 0) { out[0] = 0.f; out[1] = 0.f; }
  __shared__ int cur[NTILE];
  if (threadIdx.x < NTILE) cur[threadIdx.x] = 0;
  __syncthreads();

  int lo = b * CHUNK, hi = min(lo + CHUNK, NTOT);
  int i0 = lo + threadIdx.x * 4;
  if (i0 < hi) {  // 4-groups never straddle hi (CHUNK, NM, NT all %4==0)
    float xs[4], ys[4], lxs[4], lys[4], sxs[4], sys[4], wsv[4];
    *(float4*)xs = *(const float4*)(pos + i0);
    *(float4*)ys = *(const float4*)(pos + NTOT + i0);
    bool isTerm = (i0 >= NM && i0 < NM + NT);
    if (isTerm) {
      float nx[4], ny[4];
      *(float4*)nx = *(const float4*)(nsx + i0);
      *(float4*)ny = *(const float4*)(nsy + i0);
#pragma unroll
      for (int j = 0; j < 4; ++j) {
        float lox = fminf(fmaxf(xs[j], 0.f), 1024.f);
        float hix = fminf(fmaxf(xs[j] + nx[j], 0.f), 1024.f);
        float loy = fminf(fmaxf(ys[j], 0.f), 1024.f);
        float hiy = fminf(fmaxf(ys[j] + ny[j], 0.f), 1024.f);
        lxs[j] = lox; sxs[j] = hix - lox;
        lys[j] = loy; sys[j] = hiy - loy;
        wsv[j] = TDf;
      }
    } else {
      float oxs[4], oys[4], cx[4], cy[4], rr[4];
      *(float4*)oxs = *(const float4*)(offx + i0);
      *(float4*)oys = *(const float4*)(offy + i0);
      *(float4*)cx = *(const float4*)(csx + i0);
      *(float4*)cy = *(const float4*)(csy + i0);
      *(float4*)rr = *(const float4*)(ratio + i0);
#pragma unroll
      for (int j = 0; j < 4; ++j) {
        lxs[j] = xs[j] + oxs[j];
        lys[j] = ys[j] + oys[j];
        sxs[j] = cx[j]; sys[j] = cy[j];
        wsv[j] = rr[j];
      }
    }
#pragma unroll
    for (int j = 0; j < 4; ++j) {
      int t = tile_from_lo(lxs[j], lys[j]);
      int slot = atomicAdd(&cur[t], 1);
      int idx = (t * CBLK + b) * CAPB + min(slot, CAPB - 1);  // clamp (never hit)
      spay4[idx] = make_float4(lxs[j], lys[j], sxs[j], sys[j]);
      spayw[idx] = wsv[j];
    }
  }
  __syncthreads();
  if (threadIdx.x < NTILE)
    hcnt[threadIdx.x * CBLK + b] = min(cur[threadIdx.x], CAPB);
}

// ---------------------------------------------------------------------------
// 2) per-tile accumulation with LDS compaction map: scan the 256 sub-bucket
//    counts, build dense slot-index map (u16), iterate nodes at 100% lane
//    density. 6x6 stencil into 68x68 LDS tile, plain store to priv.
// ---------------------------------------------------------------------------
__global__ __launch_bounds__(BTHR) void k_accum(
    const int* __restrict__ hcnt, const float4* __restrict__ spay4,
    const float* __restrict__ spayw, float* __restrict__ priv) {
  __shared__ float tile[TSZ];
  __shared__ int scan[CBLK];
  __shared__ int pref[CBLK + 1];
  __shared__ unsigned short map_[MAXN];
  const int t = blockIdx.x;
  for (int j = threadIdx.x; j < TSZ; j += BTHR) tile[j] = 0.f;

  // load counts + prefix scan (Hillis-Steele over 256)
  int myCnt = 0;
  if (threadIdx.x < CBLK) {
    myCnt = hcnt[t * CBLK + threadIdx.x];
    scan[threadIdx.x] = myCnt;
  }
  __syncthreads();
  for (int d = 1; d < CBLK; d <<= 1) {
    int u = 0;
    if (threadIdx.x < CBLK && threadIdx.x >= d) u = scan[threadIdx.x - d];
    __syncthreads();
    if (threadIdx.x < CBLK) scan[threadIdx.x] += u;
    __syncthreads();
  }
  if (threadIdx.x < CBLK) {
    pref[threadIdx.x] = scan[threadIdx.x] - myCnt;  // exclusive
    if (threadIdx.x == CBLK - 1) pref[CBLK] = scan[threadIdx.x];
  }
  __syncthreads();

  // build dense map: thread b2 writes its bucket's slot ids
  if (threadIdx.x < CBLK) {
    int base0 = pref[threadIdx.x];
    int sb = threadIdx.x * CAPB;
    for (int i = 0; i < myCnt; ++i) {
      int d = base0 + i;
      if (d < MAXN) map_[d] = (unsigned short)(sb + i);
    }
  }
  __syncthreads();

  const int total = min(pref[CBLK], MAXN);
  const int bx0 = (t >> 4) << TSHIFT;
  const int by0 = (t & (TGRID - 1)) << TSHIFT;
  const int base = t * CBLK * CAPB;
  for (int d = threadIdx.x; d < total; d += BTHR) {
    int s = map_[d];
    float4 p = spay4[base + s];
    float w = spayw[base + s];
    float lx = p.x, ly = p.y;
    float hx = lx + p.z, hy = ly + p.w;
    int b0x = (int)floorf(lx);
    int b0y = (int)floorf(ly);
    float pxv[6], pyv[6];
#pragma unroll
    for (int k = 0; k < 6; ++k) {
      int kx = b0x + k;
      float px = fminf(hx, (float)kx + 1.0f) - fmaxf(lx, (float)kx);
      pxv[k] = (kx >= 0 && kx < NBX) ? fmaxf(px, 0.f) : 0.f;
      int ky = b0y + k;
      float py = fminf(hy, (float)ky + 1.0f) - fmaxf(ly, (float)ky);
      pyv[k] = (ky >= 0 && ky < NBY) ? fmaxf(py, 0.f) : 0.f;
    }
#pragma unroll
    for (int a = 0; a < 6; ++a) {
      if (pxv[a] == 0.f) continue;
      float wx = w * pxv[a];
      int lxi = b0x + a - bx0;
#pragma unroll
      for (int c = 0; c < 6; ++c) {
        float v = wx * pyv[c];
        if (v != 0.f) atomicAdd(&tile[lxi * TDIM + (b0y + c - by0)], v);
      }
    }
  }
  __syncthreads();
  float* pdst = priv + t * TSZ;
  for (int j = threadIdx.x; j < TSZ; j += BTHR) pdst[j] = tile[j];
}

// ---------------------------------------------------------------------------
// 3) combine halos + fused overflow-sum / max reduction
// ---------------------------------------------------------------------------
__global__ __launch_bounds__(BTHR) void k_final(const float* __restrict__ priv,
                                                float* __restrict__ out) {
  float ssum = 0.f, smax = 0.f;
  for (int idx = blockIdx.x * BTHR + threadIdx.x; idx < NBINS;
       idx += gridDim.x * BTHR) {
    int X = idx >> 10, Y = idx & 1023;
    int tx = X >> TSHIFT, ty = Y >> TSHIFT;
    int lx = X & (TBINS - 1), ly = Y & (TBINS - 1);
    int t = tx * TGRID + ty;
    float d = priv[t * TSZ + lx * TDIM + ly];
    if (lx < HALO && tx > 0)
      d += priv[(t - TGRID) * TSZ + (lx + TBINS) * TDIM + ly];
    if (ly < HALO && ty > 0)
      d += priv[(t - 1) * TSZ + lx * TDIM + (ly + TBINS)];
    if (lx < HALO && ly < HALO && tx > 0 && ty > 0)
      d += priv[(t - TGRID - 1) * TSZ + (lx + TBINS) * TDIM + (ly + TBINS)];
    ssum += fmaxf(d - TDf, 0.f);
    smax = fmaxf(smax, d);
  }
#pragma unroll
  for (int off = 32; off > 0; off >>= 1) {
    ssum += __shfl_down(ssum, off, 64);
    smax = fmaxf(smax, __shfl_down(smax, off, 64));
  }
  __shared__ float ss[16], sm[16];
  int wid = threadIdx.x >> 6;
  if ((threadIdx.x & 63) == 0) { ss[wid] = ssum; sm[wid] = smax; }
  __syncthreads();
  if (threadIdx.x == 0) {
    float S = 0.f, M = 0.f;
#pragma unroll
    for (int k = 0; k < 16; ++k) { S += ss[k]; M = fmaxf(M, sm[k]); }
    atomicAdd(&out[0], S);
    atomicMax((int*)&out[1], __float_as_int(M));
  }
}

// ---------------------------------------------------------------------------
// Legacy fallback (global-atomic path) if ws too small
// ---------------------------------------------------------------------------
__global__ __launch_bounds__(256) void scatter_all(
    const float* __restrict__ pos, const float* __restrict__ nsx,
    const float* __restrict__ nsy, const float* __restrict__ csx,
    const float* __restrict__ csy, const float* __restrict__ offx,
    const float* __restrict__ offy, const float* __restrict__ ratio,
    float* __restrict__ map, float* __restrict__ out) {
  int i = blockIdx.x * blockDim.x + threadIdx.x;
  if (i == 0) { out[0] = 0.f; out[1] = 0.f; }
  if (i >= NTOT) return;
  NodeGeo n = node_geo(i, pos, nsx, nsy, csx, csy, offx, offy, ratio);
  int b0x = (int)floorf(n.lx), b0y = (int)floorf(n.ly);
  float hx = n.lx + n.sx, hy = n.ly + n.sy;
  float pxv[6], pyv[6];
  int kxv[6], kyv[6];
#pragma unroll
  for (int k = 0; k < 6; ++k) {
    int kx = b0x + k;
    float px = fminf(hx, (float)kx + 1.f) - fmaxf(n.lx, (float)kx);
    pxv[k] = (kx >= 0 && kx < NBX) ? fmaxf(px, 0.f) : 0.f;
    kxv[k] = min(max(kx, 0), NBX - 1);
    int ky = b0y + k;
    float py = fminf(hy, (float)ky + 1.f) - fmaxf(n.ly, (float)ky);
    pyv[k] = (ky >= 0 && ky < NBY) ? fmaxf(py, 0.f) : 0.f;
    kyv[k] = min(max(ky, 0), NBY - 1);
  }
#pragma unroll
  for (int a = 0; a < 6; ++a) {
    if (pxv[a] == 0.f) continue;
    float wx = n.w * pxv[a];
#pragma unroll
    for (int c = 0; c < 6; ++c) {
      float v = wx * pyv[c];
      if (v != 0.f) atomicAdd(&map[kxv[a] * NBY + kyv[c]], v);
    }
  }
}

__global__ __launch_bounds__(256) void reduce_map(const float* __restrict__ map,
                                                  float* __restrict__ out) {
  const float4* m4 = (const float4*)map;
  const int n4 = NBINS / 4;
  float s = 0.f, mx = 0.f;
  for (int i = blockIdx.x * blockDim.x + threadIdx.x; i < n4;
       i += gridDim.x * blockDim.x) {
    float4 v = m4[i];
    s += fmaxf(v.x - TDf, 0.f) + fmaxf(v.y - TDf, 0.f) +
         fmaxf(v.z - TDf, 0.f) + fmaxf(v.w - TDf, 0.f);
    mx = fmaxf(mx, fmaxf(fmaxf(v.x, v.y), fmaxf(v.z, v.w)));
  }
#pragma unroll
  for (int off = 32; off > 0; off >>= 1) {
    s += __shfl_down(s, off, 64);
    mx = fmaxf(mx, __shfl_down(mx, off, 64));
  }
  __shared__ float ss[4], sm[4];
  int wid = threadIdx.x >> 6;
  if ((threadIdx.x & 63) == 0) { ss[wid] = s; sm[wid] = mx; }
  __syncthreads();
  if (threadIdx.x == 0) {
    atomicAdd(&out[0], ss[0] + ss[1] + ss[2] + ss[3]);
    atomicMax((int*)&out[1],
              __float_as_int(fmaxf(fmaxf(sm[0], sm[1]), fmaxf(sm[2], sm[3]))));
  }
}

// ---------------------------------------------------------------------------
extern "C" void kernel_launch(void* const* d_in, const int* in_sizes, int n_in,
                              void* d_out, int out_size, void* d_ws,
                              size_t ws_size, hipStream_t stream) {
  (void)in_sizes; (void)n_in; (void)out_size;
  const float* pos   = (const float*)d_in[0];
  const float* nsx   = (const float*)d_in[1];
  const float* nsy   = (const float*)d_in[2];
  const float* csx   = (const float*)d_in[3];
  const float* csy   = (const float*)d_in[4];
  const float* offx  = (const float*)d_in[5];
  const float* offy  = (const float*)d_in[6];
  const float* ratio = (const float*)d_in[7];
  float* out = (float*)d_out;
  char* ws = (char*)d_ws;

  if (ws_size >= WS_NEED) {
    int*    hcnt  = (int*)(ws + WS_HCNT);
    float*  priv  = (float*)(ws + WS_PRIV);
    float4* spay4 = (float4*)(ws + WS_SPAY4);
    float*  spayw = (float*)(ws + WS_SPAYW);

    k_fill<<<CBLK, BTHR, 0, stream>>>(pos, nsx, nsy, csx, csy, offx, offy,
                                      ratio, hcnt, spay4, spayw, out);
    k_accum<<<NTILE, BTHR, 0, stream>>>(hcnt, spay4, spayw, priv);
    k_final<<<256, BTHR, 0, stream>>>(priv, out);
  } else {
    float* map = (float*)ws;
    hipMemsetAsync(map, 0, NBINS * sizeof(float), stream);
    scatter_all<<<(NTOT + 255) / 256, 256, 0, stream>>>(
        pos, nsx, nsy, csx, csy, offx, offy, ratio, map, out);
    reduce_map<<<1024, 256, 0, stream>>>(map, out);
  }
}